// Round 1
// baseline (209.701 us; speedup 1.0000x reference)
//
#include <hip/hip_runtime.h>
#include <hip/hip_bf16.h>

#define C 64   // C_IN == C_OUT == 64
#define NCOPY 8
#define PADU64 8                       // u64s per counter slot: 64B/counter (line-conflict experiment)
#define FXSCALE 16777216.0f            // 2^24
#define LOW44 ((1ULL << 44) - 1)

typedef unsigned short u16;

__device__ __forceinline__ u16 f2bf_rne(float v) {
    unsigned u = __float_as_uint(v);
    u += 0x7FFFu + ((u >> 16) & 1u);
    return (u16)(u >> 16);
}
__device__ __forceinline__ float bf2f(u16 u) {
    return __uint_as_float((unsigned)u << 16);
}

// --- Kernel 1: fused histogram (x4 unrolled) + x->bf16 convert.
// One u64 atomic per edge: bits [44:63] = count, [0:43] = fixed-point sum(ew).
// Counter slots padded to one per 64B cache line (stride PADU64 u64s).
// Return value's high bits = this edge's rank within (copy,row).
__global__ __launch_bounds__(256) void hist8_kernel(const int* __restrict__ row,
                                                    const float* __restrict__ ew,
                                                    unsigned long long* __restrict__ cd8,
                                                    int* __restrict__ rank,
                                                    const float* __restrict__ x,
                                                    u16* __restrict__ xh,
                                                    int E, int N, int total4, int nthreads) {
    int t = threadIdx.x;
    int base = blockIdx.x * 1024;
    int copy = blockIdx.x & (NCOPY - 1);
    size_t cb = (size_t)copy * N;

    unsigned long long old[4];
    int e[4];
#pragma unroll
    for (int u = 0; u < 4; u++) {
        e[u] = base + u * 256 + t;
        if (e[u] < E) {
            int r = row[e[u]];
            unsigned long long fx = (unsigned long long)__float2uint_rn(ew[e[u]] * FXSCALE);
            unsigned long long inc = (1ULL << 44) | fx;
            old[u] = atomicAdd(&cd8[(cb + r) * PADU64], inc);
        }
    }
#pragma unroll
    for (int u = 0; u < 4; u++) {
        if (e[u] < E) rank[e[u]] = (int)(old[u] >> 44);
    }

    // fused x -> bf16 convert (grid-stride)
    int gtid = blockIdx.x * 256 + t;
    for (int i = gtid; i < total4; i += nthreads) {
        float4 v = *(const float4*)(x + (size_t)i * 4);
        ushort4 o;
        o.x = f2bf_rne(v.x); o.y = f2bf_rne(v.y);
        o.z = f2bf_rne(v.z); o.w = f2bf_rne(v.w);
        *(ushort4*)(xh + (size_t)i * 4) = o;
    }
}

// --- Scan phase A: reduce 8 padded copies -> cnt, dis; dense per-copy counts
// (cnt8d) so later phases never re-read the padded buffer; per-block sums of cnt.
__global__ __launch_bounds__(256) void scanA_kernel(const unsigned long long* __restrict__ cd8,
                                                    int* __restrict__ cnt,
                                                    int* __restrict__ cnt8d,
                                                    float* __restrict__ dis,
                                                    int* __restrict__ bsum, int N) {
    __shared__ int s[256];
    int t = threadIdx.x;
    int i = blockIdx.x * 256 + t;
    int cv = 0;
    unsigned long long dfx = 0;
    if (i < N) {
#pragma unroll
        for (int c = 0; c < NCOPY; c++) {
            unsigned long long v = cd8[((size_t)c * N + i) * PADU64];
            int cc = (int)(v >> 44);
            cv += cc;
            dfx += (v & LOW44);
            cnt8d[(size_t)c * N + i] = cc;
        }
        cnt[i] = cv;
        float dv = (float)dfx * (1.0f / FXSCALE);
        dis[i] = (dv > 0.0f) ? rsqrtf(dv) : 0.0f;
    }
    s[t] = cv;
    __syncthreads();
    for (int off = 128; off > 0; off >>= 1) {
        if (t < off) s[t] += s[t + off];
        __syncthreads();
    }
    if (t == 0) bsum[blockIdx.x] = s[0];
}

// --- Scan phase C (scanB fused in): every block redoes the <=256-entry
// block-sum scan in LDS, then does its per-element scan. Writes rowptr and
// per-copy start slots (atomic-free scatter prep).
__global__ __launch_bounds__(256) void scanC_kernel(const int* __restrict__ cnt,
                                                    const int* __restrict__ cnt8d,
                                                    int* __restrict__ start8,
                                                    const int* __restrict__ bsum,
                                                    int* __restrict__ rowptr, int N, int G) {
    __shared__ int sb[256];
    __shared__ int s[256];
    int t = threadIdx.x;

    // inclusive scan of block sums (G <= 256)
    int bv = (t < G) ? bsum[t] : 0;
    sb[t] = bv;
    __syncthreads();
    for (int off = 1; off < 256; off <<= 1) {
        int u = (t >= off) ? sb[t - off] : 0;
        __syncthreads();
        sb[t] += u;
        __syncthreads();
    }
    int bpre = (blockIdx.x == 0) ? 0 : sb[blockIdx.x - 1];
    if (blockIdx.x == 0 && t == 0) rowptr[N] = sb[G - 1];   // total edge count

    // per-element inclusive scan of this block's cnt
    int i = blockIdx.x * 256 + t;
    int v = (i < N) ? cnt[i] : 0;
    s[t] = v;
    __syncthreads();
    for (int off = 1; off < 256; off <<= 1) {
        int u = (t >= off) ? s[t - off] : 0;
        __syncthreads();
        s[t] += u;
        __syncthreads();
    }
    if (i < N) {
        int rp = bpre + s[t] - v;  // exclusive prefix
        rowptr[i] = rp;
        int run = rp;
#pragma unroll
        for (int c = 0; c < NCOPY; c++) {
            int tmp = cnt8d[(size_t)c * N + i];
            start8[(size_t)c * N + i] = run;   // start slot for this copy
            run += tmp;
        }
    }
}

// --- Kernel 4: atomic-free scatter (x4 unrolled, same copy mapping as hist) ---
__global__ __launch_bounds__(256) void scatter_kernel(const int* __restrict__ row,
                                                      const int* __restrict__ col,
                                                      const float* __restrict__ ew,
                                                      const float* __restrict__ dis,
                                                      const int* __restrict__ start8,
                                                      const int* __restrict__ rank,
                                                      float2* __restrict__ ewc,
                                                      int E, int N) {
    int t = threadIdx.x;
    int base = blockIdx.x * 1024;
    int copy = blockIdx.x & (NCOPY - 1);
    size_t cb = (size_t)copy * N;
#pragma unroll
    for (int u = 0; u < 4; u++) {
        int e = base + u * 256 + t;
        if (e < E) {
            int r = row[e];
            int c = col[e];
            float wv = -dis[r] * ew[e] * dis[c];
            int pos = start8[cb + r] + rank[e];
            ewc[pos] = make_float2(wv, __int_as_float(c));
        }
    }
}

// --- Kernel 5: CSR SpMM, 2 edges per wave (half-wave per edge), bf16x2 gathers.
// lane = (half, chpair): half-wave h processes edges j+h; lane loads one u32
// (2 bf16 channels). One VMEM instruction serves 2 edges (256B).
__global__ __launch_bounds__(256) void spmm_csr_kernel(
        const int* __restrict__ rowptr,
        const float2* __restrict__ ewc,
        const unsigned* __restrict__ h32,   // bf16x2 [N][32]
        float* __restrict__ out32,          // fp32 [N][C]
        unsigned* __restrict__ outbf,       // bf16x2 [N][32]
        int N) {
    int wid = (blockIdx.x * blockDim.x + threadIdx.x) >> 6;  // row id
    int lane = threadIdx.x & 63;
    if (wid >= N) return;
    int half = lane >> 5;        // which edge of the pair
    int cp   = lane & 31;        // channel pair 0..31
    int beg = rowptr[wid];
    int end = rowptr[wid + 1];
    float ax0 = 0.f, ay0 = 0.f, ax1 = 0.f, ay1 = 0.f;
    float ax2 = 0.f, ay2 = 0.f, ax3 = 0.f, ay3 = 0.f;
    for (int base = beg; base < end; base += 64) {
        int idx = base + lane;
        // zero-pad: w=0, col=0 -> harmless gather of row 0
        float2 ed = (idx < end) ? ewc[idx] : make_float2(0.0f, __int_as_float(0));
        int cnt = end - base; if (cnt > 64) cnt = 64;
        for (int j = 0; j < cnt; j += 8) {
            int s0 = j + half;
            int s1 = j + 2 + half;
            int s2 = j + 4 + half;
            int s3 = j + 6 + half;
            float w0 = __shfl(ed.x, s0);
            int   c0 = __shfl(__float_as_int(ed.y), s0);
            float w1 = __shfl(ed.x, s1);
            int   c1 = __shfl(__float_as_int(ed.y), s1);
            float w2 = __shfl(ed.x, s2);
            int   c2 = __shfl(__float_as_int(ed.y), s2);
            float w3 = __shfl(ed.x, s3);
            int   c3 = __shfl(__float_as_int(ed.y), s3);
            unsigned hv0 = h32[(size_t)c0 * 32 + cp];
            unsigned hv1 = h32[(size_t)c1 * 32 + cp];
            unsigned hv2 = h32[(size_t)c2 * 32 + cp];
            unsigned hv3 = h32[(size_t)c3 * 32 + cp];
            ax0 = fmaf(w0, bf2f((u16)(hv0 & 0xffffu)), ax0);
            ay0 = fmaf(w0, bf2f((u16)(hv0 >> 16)),     ay0);
            ax1 = fmaf(w1, bf2f((u16)(hv1 & 0xffffu)), ax1);
            ay1 = fmaf(w1, bf2f((u16)(hv1 >> 16)),     ay1);
            ax2 = fmaf(w2, bf2f((u16)(hv2 & 0xffffu)), ax2);
            ay2 = fmaf(w2, bf2f((u16)(hv2 >> 16)),     ay2);
            ax3 = fmaf(w3, bf2f((u16)(hv3 & 0xffffu)), ax3);
            ay3 = fmaf(w3, bf2f((u16)(hv3 >> 16)),     ay3);
        }
    }
    float ax = (ax0 + ax1) + (ax2 + ax3);
    float ay = (ay0 + ay1) + (ay2 + ay3);
    // combine the two half-waves
    float bx = __shfl(ax, cp + 32);
    float by = __shfl(ay, cp + 32);
    if (half == 0) {
        float rx = ax + bx;
        float ry = ay + by;
        *(float2*)(out32 + (size_t)wid * C + 2 * cp) = make_float2(rx, ry);
        unsigned pk = (unsigned)f2bf_rne(rx) | ((unsigned)f2bf_rne(ry) << 16);
        outbf[(size_t)wid * 32 + cp] = pk;
    }
}

// --- Kernel 6: fused dense epilogue as register-tiled GEMM ---
// out = relu([x | T1 | 2P-x] @ Wcat + b), Wcat = [192][64] (W row-major)
__global__ __launch_bounds__(256) void final_gemm_kernel(
        const float* __restrict__ x,
        const float* __restrict__ T1,
        const float* __restrict__ P,
        const float* __restrict__ W,   // [192][64] row-major
        const float* __restrict__ b,
        float* __restrict__ out, int N) {
    __shared__ float As[16][64];  // [k][node]
    __shared__ float Ws[16][64];  // [k][col]

    int t  = threadIdx.x;
    int tx = t & 15;
    int ty = t >> 4;
    int n0 = blockIdx.x * 64;

    int sn = t >> 2;
    int skb = (t & 3) * 4;

    float acc[4][4];
#pragma unroll
    for (int i = 0; i < 4; i++)
#pragma unroll
        for (int j = 0; j < 4; j++) acc[i][j] = 0.0f;

#pragma unroll 1
    for (int s = 0; s < 12; s++) {
        float4 wv = *(const float4*)(W + s * 1024 + t * 4);
        int nn = n0 + sn;
        float4 av = make_float4(0.f, 0.f, 0.f, 0.f);
        if (nn < N) {
            if (s < 4) {
                av = *(const float4*)(x + (size_t)nn * C + s * 16 + skb);
            } else if (s < 8) {
                av = *(const float4*)(T1 + (size_t)nn * C + (s - 4) * 16 + skb);
            } else {
                float4 pv = *(const float4*)(P + (size_t)nn * C + (s - 8) * 16 + skb);
                float4 xv = *(const float4*)(x + (size_t)nn * C + (s - 8) * 16 + skb);
                av = make_float4(2.0f * pv.x - xv.x, 2.0f * pv.y - xv.y,
                                 2.0f * pv.z - xv.z, 2.0f * pv.w - xv.w);
            }
        }
        __syncthreads();
        {
            int wk = (t * 4) >> 6;
            int wc = (t * 4) & 63;
            *(float4*)&Ws[wk][wc] = wv;
        }
        As[skb + 0][sn] = av.x;
        As[skb + 1][sn] = av.y;
        As[skb + 2][sn] = av.z;
        As[skb + 3][sn] = av.w;
        __syncthreads();

#pragma unroll
        for (int kk = 0; kk < 16; kk++) {
            float4 a4 = *(const float4*)&As[kk][ty * 4];
            float4 w4 = *(const float4*)&Ws[kk][tx * 4];
            float ar[4] = {a4.x, a4.y, a4.z, a4.w};
            float wr[4] = {w4.x, w4.y, w4.z, w4.w};
#pragma unroll
            for (int i = 0; i < 4; i++)
#pragma unroll
                for (int j = 0; j < 4; j++)
                    acc[i][j] = fmaf(ar[i], wr[j], acc[i][j]);
        }
    }

    float4 bv = *(const float4*)(b + tx * 4);
    float br[4] = {bv.x, bv.y, bv.z, bv.w};
#pragma unroll
    for (int i = 0; i < 4; i++) {
        int node = n0 + ty * 4 + i;
        if (node < N) {
            float4 o;
            o.x = fmaxf(acc[i][0] + br[0], 0.0f);
            o.y = fmaxf(acc[i][1] + br[1], 0.0f);
            o.z = fmaxf(acc[i][2] + br[2], 0.0f);
            o.w = fmaxf(acc[i][3] + br[3], 0.0f);
            *(float4*)(out + (size_t)node * C + tx * 4) = o;
        }
    }
}

extern "C" void kernel_launch(void* const* d_in, const int* in_sizes, int n_in,
                              void* d_out, int out_size, void* d_ws, size_t ws_size,
                              hipStream_t stream) {
    const float* x  = (const float*)d_in[0];
    const int*   ei = (const int*)d_in[1];
    const float* ew = (const float*)d_in[2];
    const float* W  = (const float*)d_in[3];
    const float* b  = (const float*)d_in[4];
    float* out = (float*)d_out;

    const int N = in_sizes[0] / C;
    const int E = in_sizes[2];
    const int* row = ei;        // edge_index[0]
    const int* col = ei + E;    // edge_index[1]

    char* ws = (char*)d_ws;
    size_t off = 0;
    auto alloc = [&](size_t bytes) {
        void* p = ws + off;
        off = (off + bytes + 255) & ~(size_t)255;
        return p;
    };
    float*  dis    = (float*)alloc((size_t)N * 4);
    int*    cnt    = (int*)alloc((size_t)N * 4);
    int*    rowptr = (int*)alloc((size_t)(N + 1) * 4);
    float2* ewc    = (float2*)alloc((size_t)E * 8);
    float*  T1     = (float*)alloc((size_t)N * C * 4);
    float*  P      = (float*)alloc((size_t)N * C * 4);
    int*    bsum   = (int*)alloc((size_t)256 * 4);
    unsigned long long* cd8 = (unsigned long long*)alloc((size_t)NCOPY * N * 8 * PADU64);
    int*    start8 = (int*)alloc((size_t)NCOPY * N * 4);
    int*    cnt8d  = (int*)alloc((size_t)NCOPY * N * 4);
    int*    rank   = (int*)alloc((size_t)E * 4);
    u16*    xh     = (u16*)alloc((size_t)N * C * 2);
    u16*    T1h    = (u16*)alloc((size_t)N * C * 2);
    u16*    Ph     = (u16*)alloc((size_t)N * C * 2);  // bf16 sink for spmm2

    hipMemsetAsync(cd8, 0, (size_t)NCOPY * N * 8 * PADU64, stream);

    const int B = 256;
    const int G = (N + B - 1) / B;  // 196 <= 256

    int histBlocks = (E + 1023) / 1024;
    int total4 = N * C / 4;
    hist8_kernel<<<histBlocks, B, 0, stream>>>(row, ew, cd8, rank, x, xh,
                                               E, N, total4, histBlocks * B);
    scanA_kernel<<<G, B, 0, stream>>>(cd8, cnt, cnt8d, dis, bsum, N);
    scanC_kernel<<<G, B, 0, stream>>>(cnt, cnt8d, start8, bsum, rowptr, N, G);
    scatter_kernel<<<histBlocks, B, 0, stream>>>(row, col, ew, dis, start8,
                                                 rank, ewc, E, N);

    int spmm_blocks = (int)(((long long)N * 64 + B - 1) / B);
    spmm_csr_kernel<<<spmm_blocks, B, 0, stream>>>(rowptr, ewc, (const unsigned*)xh,
                                                   T1, (unsigned*)T1h, N);
    spmm_csr_kernel<<<spmm_blocks, B, 0, stream>>>(rowptr, ewc, (const unsigned*)T1h,
                                                   P, (unsigned*)Ph, N);

    final_gemm_kernel<<<(N + 63) / 64, B, 0, stream>>>(x, T1, P, W, b, out, N);
}

// Round 3
// 182.649 us; speedup vs baseline: 1.1481x; 1.1481x over previous
//
#include <hip/hip_runtime.h>
#include <hip/hip_bf16.h>

#define C 64   // C_IN == C_OUT == 64

typedef unsigned short u16;
typedef unsigned int u32;
typedef unsigned long long u64;

__device__ __forceinline__ u16 f2bf_rne(float v) {
    unsigned u = __float_as_uint(v);
    u += 0x7FFFu + ((u >> 16) & 1u);
    return (u16)(u >> 16);
}
__device__ __forceinline__ float bf2f(u16 u) {
    return __uint_as_float((unsigned)u << 16);
}

// ============================================================================
// Atomic-free CSR build: MSD bucket sort by row>>8 (256 buckets), then
// per-bucket counting sort by row&255. No global atomics anywhere.
// ============================================================================

// --- P1 hist: per-block 256-bin LDS histogram of row>>8; fused x->bf16 ---
__global__ __launch_bounds__(256) void p1hist_kernel(const int* __restrict__ row,
                                                     u32* __restrict__ hoff,  // [NB][256]
                                                     const float* __restrict__ x,
                                                     u16* __restrict__ xh,
                                                     int E, int NB, int total4, int nthreads) {
    __shared__ u32 h[256];
    int t = threadIdx.x;
    int b = blockIdx.x;
    h[t] = 0;
    __syncthreads();
    int base = b * 1024;
#pragma unroll
    for (int u = 0; u < 4; u++) {
        int e = base + u * 256 + t;
        if (e < E) {
            int r = row[e];
            atomicAdd(&h[r >> 8], 1u);
        }
    }
    __syncthreads();
    hoff[(size_t)b * 256 + t] = h[t];   // block-major, coalesced

    // fused x -> bf16 convert (grid-stride)
    int gtid = b * 256 + t;
    for (int i = gtid; i < total4; i += nthreads) {
        float4 v = *(const float4*)(x + (size_t)i * 4);
        ushort4 o;
        o.x = f2bf_rne(v.x); o.y = f2bf_rne(v.y);
        o.z = f2bf_rne(v.z); o.w = f2bf_rne(v.w);
        *(ushort4*)(xh + (size_t)i * 4) = o;
    }
}

// --- scanA: one block per digit d; exclusive scan of hoff[b][d] over blocks
// (in-place), digit total -> T[d]. ---
__global__ __launch_bounds__(256) void scanA_kernel(u32* __restrict__ hoff,
                                                    u32* __restrict__ T, int NB) {
    __shared__ u32 s[256];
    int t = threadIdx.x;
    int d = blockIdx.x;
    u32 carry = 0;
    int nchunk = (NB + 255) / 256;
    for (int ch = 0; ch < nchunk; ch++) {
        int idx = ch * 256 + t;
        u32 v = (idx < NB) ? hoff[(size_t)idx * 256 + d] : 0;
        s[t] = v;
        __syncthreads();
        for (int off = 1; off < 256; off <<= 1) {
            u32 u = (t >= off) ? s[t - off] : 0;
            __syncthreads();
            s[t] += u;
            __syncthreads();
        }
        if (idx < NB) hoff[(size_t)idx * 256 + d] = carry + s[t] - v;  // exclusive
        u32 tot = s[255];
        __syncthreads();
        carry += tot;
    }
    if (t == 0) T[d] = carry;
}

// --- scanB: exclusive scan of 256 digit totals -> Tpre[257]; rowptr[N]=E ---
__global__ __launch_bounds__(256) void scanB_kernel(const u32* __restrict__ T,
                                                    u32* __restrict__ Tpre,
                                                    int* __restrict__ rowptr, int N) {
    __shared__ u32 s[256];
    int t = threadIdx.x;
    u32 v = T[t];
    s[t] = v;
    __syncthreads();
    for (int off = 1; off < 256; off <<= 1) {
        u32 u = (t >= off) ? s[t - off] : 0;
        __syncthreads();
        s[t] += u;
        __syncthreads();
    }
    Tpre[t] = s[t] - v;
    if (t == 255) {
        Tpre[256] = s[255];
        rowptr[N] = (int)s[255];
    }
}

// --- P1 scatter: place edges into their row>>8 bucket. Within-bucket order
// arbitrary (LDS returning atomics) — legal for an MSD pass. Payload packs
// (row<<16)|col in high 32 bits, ew bits in low 32. ---
__global__ __launch_bounds__(256) void p1scatter_kernel(const int* __restrict__ row,
                                                        const int* __restrict__ col,
                                                        const float* __restrict__ ew,
                                                        const u32* __restrict__ hoff, // [NB][256] excl
                                                        const u32* __restrict__ Tpre,
                                                        u64* __restrict__ pay,
                                                        int E) {
    __shared__ u32 cur[256];
    int t = threadIdx.x;
    int b = blockIdx.x;
    cur[t] = Tpre[t] + hoff[(size_t)b * 256 + t];
    __syncthreads();
    int base = b * 1024;
#pragma unroll
    for (int u = 0; u < 4; u++) {
        int e = base + u * 256 + t;
        if (e < E) {
            u32 r = (u32)row[e];
            u32 c = (u32)col[e];
            u32 rc = (r << 16) | c;
            u32 pos = atomicAdd(&cur[r >> 8], 1u);
            pay[pos] = ((u64)rc << 32) | (u64)__float_as_uint(ew[e]);
        }
    }
}

// --- P2: per-bucket counting sort by row&255 into final CSR; writes rowptr
// for this bucket's 256 rows, deg sums (LDS f32 atomics) -> dis. ---
__global__ __launch_bounds__(256) void p2_kernel(const u64* __restrict__ pay,
                                                 const u32* __restrict__ Tpre,
                                                 int* __restrict__ rowptr,
                                                 float* __restrict__ dis,
                                                 float2* __restrict__ ewc,
                                                 int N) {
    __shared__ u32 h[256];
    __shared__ u32 s[256];
    __shared__ u32 cur[256];
    __shared__ float dsum[256];
    int t = threadIdx.x;
    int bk = blockIdx.x;
    u32 base = Tpre[bk];
    u32 cnt = Tpre[bk + 1] - base;

    h[t] = 0;
    dsum[t] = 0.0f;
    __syncthreads();
    for (u32 j = t; j < cnt; j += 256) {
        u64 v = pay[base + j];
        u32 lr = (u32)(v >> 48) & 255u;   // row & 255 (row>>8 == bk here)
        atomicAdd(&h[lr], 1u);
    }
    __syncthreads();
    // exclusive scan of h
    u32 hv = h[t];
    s[t] = hv;
    __syncthreads();
    for (int off = 1; off < 256; off <<= 1) {
        u32 u = (t >= off) ? s[t - off] : 0;
        __syncthreads();
        s[t] += u;
        __syncthreads();
    }
    u32 p = s[t] - hv;   // exclusive
    int r = bk * 256 + t;
    if (r < N) rowptr[r] = (int)(base + p);
    cur[t] = base + p;
    __syncthreads();
    for (u32 j = t; j < cnt; j += 256) {
        u64 v = pay[base + j];
        u32 rc = (u32)(v >> 32);
        u32 lr = (rc >> 16) & 255u;
        float w = __uint_as_float((u32)v);
        u32 pos = atomicAdd(&cur[lr], 1u);
        ewc[pos] = make_float2(w, __uint_as_float(rc));
        atomicAdd(&dsum[lr], w);
    }
    __syncthreads();
    if (r < N) {
        float dv = dsum[t];
        dis[r] = (dv > 0.0f) ? rsqrtf(dv) : 0.0f;
    }
}

// --- W: apply Laplacian normalization in place: w = -dis[r]*ew*dis[c].
// Keeps (row<<16)|col in .y (SpMM masks out col). ---
__global__ __launch_bounds__(256) void wnorm_kernel(float2* __restrict__ ewc,
                                                    const float* __restrict__ dis,
                                                    int E) {
    int t = threadIdx.x;
    int base = blockIdx.x * 1024;
#pragma unroll
    for (int u = 0; u < 4; u++) {
        int e = base + u * 256 + t;
        if (e < E) {
            float2 f = ewc[e];
            u32 rc = __float_as_uint(f.y);
            u32 r = rc >> 16;
            u32 c = rc & 0xffffu;
            float w = -dis[r] * f.x * dis[c];
            ewc[e] = make_float2(w, f.y);
        }
    }
}

// --- CSR SpMM, 2 edges per wave (half-wave per edge), bf16x2 gathers.
// lane = (half, chpair): half-wave h processes edges j+h; lane loads one u32
// (2 bf16 channels). One VMEM instruction serves 2 edges (256B). ---
__global__ __launch_bounds__(256) void spmm_csr_kernel(
        const int* __restrict__ rowptr,
        const float2* __restrict__ ewc,
        const unsigned* __restrict__ h32,   // bf16x2 [N][32]
        float* __restrict__ out32,          // fp32 [N][C]
        unsigned* __restrict__ outbf,       // bf16x2 [N][32]
        int N) {
    int wid = (blockIdx.x * blockDim.x + threadIdx.x) >> 6;  // row id
    int lane = threadIdx.x & 63;
    if (wid >= N) return;
    int half = lane >> 5;        // which edge of the pair
    int cp   = lane & 31;        // channel pair 0..31
    int beg = rowptr[wid];
    int end = rowptr[wid + 1];
    float ax0 = 0.f, ay0 = 0.f, ax1 = 0.f, ay1 = 0.f;
    float ax2 = 0.f, ay2 = 0.f, ax3 = 0.f, ay3 = 0.f;
    for (int base = beg; base < end; base += 64) {
        int idx = base + lane;
        // zero-pad: w=0, col=0 -> harmless gather of row 0
        float2 ed = (idx < end) ? ewc[idx] : make_float2(0.0f, __int_as_float(0));
        int cnt = end - base; if (cnt > 64) cnt = 64;
        for (int j = 0; j < cnt; j += 8) {
            int s0 = j + half;
            int s1 = j + 2 + half;
            int s2 = j + 4 + half;
            int s3 = j + 6 + half;
            float w0 = __shfl(ed.x, s0);
            int   c0 = __shfl(__float_as_int(ed.y), s0) & 0xffff;
            float w1 = __shfl(ed.x, s1);
            int   c1 = __shfl(__float_as_int(ed.y), s1) & 0xffff;
            float w2 = __shfl(ed.x, s2);
            int   c2 = __shfl(__float_as_int(ed.y), s2) & 0xffff;
            float w3 = __shfl(ed.x, s3);
            int   c3 = __shfl(__float_as_int(ed.y), s3) & 0xffff;
            unsigned hv0 = h32[(size_t)c0 * 32 + cp];
            unsigned hv1 = h32[(size_t)c1 * 32 + cp];
            unsigned hv2 = h32[(size_t)c2 * 32 + cp];
            unsigned hv3 = h32[(size_t)c3 * 32 + cp];
            ax0 = fmaf(w0, bf2f((u16)(hv0 & 0xffffu)), ax0);
            ay0 = fmaf(w0, bf2f((u16)(hv0 >> 16)),     ay0);
            ax1 = fmaf(w1, bf2f((u16)(hv1 & 0xffffu)), ax1);
            ay1 = fmaf(w1, bf2f((u16)(hv1 >> 16)),     ay1);
            ax2 = fmaf(w2, bf2f((u16)(hv2 & 0xffffu)), ax2);
            ay2 = fmaf(w2, bf2f((u16)(hv2 >> 16)),     ay2);
            ax3 = fmaf(w3, bf2f((u16)(hv3 & 0xffffu)), ax3);
            ay3 = fmaf(w3, bf2f((u16)(hv3 >> 16)),     ay3);
        }
    }
    float ax = (ax0 + ax1) + (ax2 + ax3);
    float ay = (ay0 + ay1) + (ay2 + ay3);
    // combine the two half-waves
    float bx = __shfl(ax, cp + 32);
    float by = __shfl(ay, cp + 32);
    if (half == 0) {
        float rx = ax + bx;
        float ry = ay + by;
        *(float2*)(out32 + (size_t)wid * C + 2 * cp) = make_float2(rx, ry);
        unsigned pk = (unsigned)f2bf_rne(rx) | ((unsigned)f2bf_rne(ry) << 16);
        outbf[(size_t)wid * 32 + cp] = pk;
    }
}

// --- fused dense epilogue as register-tiled GEMM ---
// out = relu([x | T1 | 2P-x] @ Wcat + b), Wcat = [192][64] (W row-major)
__global__ __launch_bounds__(256) void final_gemm_kernel(
        const float* __restrict__ x,
        const float* __restrict__ T1,
        const float* __restrict__ P,
        const float* __restrict__ W,   // [192][64] row-major
        const float* __restrict__ b,
        float* __restrict__ out, int N) {
    __shared__ float As[16][64];  // [k][node]
    __shared__ float Ws[16][64];  // [k][col]

    int t  = threadIdx.x;
    int tx = t & 15;
    int ty = t >> 4;
    int n0 = blockIdx.x * 64;

    int sn = t >> 2;
    int skb = (t & 3) * 4;

    float acc[4][4];
#pragma unroll
    for (int i = 0; i < 4; i++)
#pragma unroll
        for (int j = 0; j < 4; j++) acc[i][j] = 0.0f;

#pragma unroll 1
    for (int s = 0; s < 12; s++) {
        float4 wv = *(const float4*)(W + s * 1024 + t * 4);
        int nn = n0 + sn;
        float4 av = make_float4(0.f, 0.f, 0.f, 0.f);
        if (nn < N) {
            if (s < 4) {
                av = *(const float4*)(x + (size_t)nn * C + s * 16 + skb);
            } else if (s < 8) {
                av = *(const float4*)(T1 + (size_t)nn * C + (s - 4) * 16 + skb);
            } else {
                float4 pv = *(const float4*)(P + (size_t)nn * C + (s - 8) * 16 + skb);
                float4 xv = *(const float4*)(x + (size_t)nn * C + (s - 8) * 16 + skb);
                av = make_float4(2.0f * pv.x - xv.x, 2.0f * pv.y - xv.y,
                                 2.0f * pv.z - xv.z, 2.0f * pv.w - xv.w);
            }
        }
        __syncthreads();
        {
            int wk = (t * 4) >> 6;
            int wc = (t * 4) & 63;
            *(float4*)&Ws[wk][wc] = wv;
        }
        As[skb + 0][sn] = av.x;
        As[skb + 1][sn] = av.y;
        As[skb + 2][sn] = av.z;
        As[skb + 3][sn] = av.w;
        __syncthreads();

#pragma unroll
        for (int kk = 0; kk < 16; kk++) {
            float4 a4 = *(const float4*)&As[kk][ty * 4];
            float4 w4 = *(const float4*)&Ws[kk][tx * 4];
            float ar[4] = {a4.x, a4.y, a4.z, a4.w};
            float wr[4] = {w4.x, w4.y, w4.z, w4.w};
#pragma unroll
            for (int i = 0; i < 4; i++)
#pragma unroll
                for (int j = 0; j < 4; j++)
                    acc[i][j] = fmaf(ar[i], wr[j], acc[i][j]);
        }
    }

    float4 bv = *(const float4*)(b + tx * 4);
    float br[4] = {bv.x, bv.y, bv.z, bv.w};
#pragma unroll
    for (int i = 0; i < 4; i++) {
        int node = n0 + ty * 4 + i;
        if (node < N) {
            float4 o;
            o.x = fmaxf(acc[i][0] + br[0], 0.0f);
            o.y = fmaxf(acc[i][1] + br[1], 0.0f);
            o.z = fmaxf(acc[i][2] + br[2], 0.0f);
            o.w = fmaxf(acc[i][3] + br[3], 0.0f);
            *(float4*)(out + (size_t)node * C + tx * 4) = o;
        }
    }
}

extern "C" void kernel_launch(void* const* d_in, const int* in_sizes, int n_in,
                              void* d_out, int out_size, void* d_ws, size_t ws_size,
                              hipStream_t stream) {
    const float* x  = (const float*)d_in[0];
    const int*   ei = (const int*)d_in[1];
    const float* ew = (const float*)d_in[2];
    const float* W  = (const float*)d_in[3];
    const float* b  = (const float*)d_in[4];
    float* out = (float*)d_out;

    const int N = in_sizes[0] / C;
    const int E = in_sizes[2];
    const int* row = ei;        // edge_index[0]
    const int* col = ei + E;    // edge_index[1]

    char* ws = (char*)d_ws;
    size_t off = 0;
    auto alloc = [&](size_t bytes) {
        void* p = ws + off;
        off = (off + bytes + 255) & ~(size_t)255;
        return p;
    };
    const int NB = (E + 1023) / 1024;        // histogram/partition blocks
    const int NBUCK = (N + 255) / 256;       // row buckets (196)

    float*  dis    = (float*)alloc((size_t)N * 4);
    int*    rowptr = (int*)alloc((size_t)(N + 1) * 4);
    float2* ewc    = (float2*)alloc((size_t)E * 8);
    u64*    pay    = (u64*)alloc((size_t)E * 8);
    float*  T1     = (float*)alloc((size_t)N * C * 4);
    float*  P      = (float*)alloc((size_t)N * C * 4);
    u32*    hoff   = (u32*)alloc((size_t)NB * 256 * 4);
    u32*    T      = (u32*)alloc((size_t)256 * 4);
    u32*    Tpre   = (u32*)alloc((size_t)257 * 4);
    u16*    xh     = (u16*)alloc((size_t)N * C * 2);
    u16*    T1h    = (u16*)alloc((size_t)N * C * 2);
    u16*    Ph     = (u16*)alloc((size_t)N * C * 2);  // bf16 sink for spmm2

    const int B = 256;
    int total4 = N * C / 4;

    p1hist_kernel<<<NB, B, 0, stream>>>(row, hoff, x, xh, E, NB, total4, NB * B);
    scanA_kernel<<<256, B, 0, stream>>>(hoff, T, NB);
    scanB_kernel<<<1, B, 0, stream>>>(T, Tpre, rowptr, N);
    p1scatter_kernel<<<NB, B, 0, stream>>>(row, col, ew, hoff, Tpre, pay, E);
    p2_kernel<<<NBUCK, B, 0, stream>>>(pay, Tpre, rowptr, dis, ewc, N);
    wnorm_kernel<<<NB, B, 0, stream>>>(ewc, dis, E);

    int spmm_blocks = (int)(((long long)N * 64 + B - 1) / B);
    spmm_csr_kernel<<<spmm_blocks, B, 0, stream>>>(rowptr, ewc, (const unsigned*)xh,
                                                   T1, (unsigned*)T1h, N);
    spmm_csr_kernel<<<spmm_blocks, B, 0, stream>>>(rowptr, ewc, (const unsigned*)T1h,
                                                   P, (unsigned*)Ph, N);

    final_gemm_kernel<<<(N + 63) / 64, B, 0, stream>>>(x, T1, P, W, b, out, N);
}

// Round 4
// 177.052 us; speedup vs baseline: 1.1844x; 1.0316x over previous
//
#include <hip/hip_runtime.h>
#include <hip/hip_bf16.h>

#define C 64   // C_IN == C_OUT == 64

typedef unsigned short u16;
typedef unsigned int u32;
typedef unsigned long long u64;

__device__ __forceinline__ u16 f2bf_rne(float v) {
    unsigned u = __float_as_uint(v);
    u += 0x7FFFu + ((u >> 16) & 1u);
    return (u16)(u >> 16);
}
__device__ __forceinline__ float bf2f(u16 u) {
    return __uint_as_float((unsigned)u << 16);
}

// ============================================================================
// Atomic-free CSR build: MSD bucket sort by row>>8 (256 buckets), then
// per-bucket counting sort by row&255. No global atomics anywhere.
// ============================================================================

// --- P1 hist: per-block 256-bin LDS histogram of row>>8; fused x->bf16 ---
__global__ __launch_bounds__(256) void p1hist_kernel(const int* __restrict__ row,
                                                     u32* __restrict__ hoff,  // [NB][256]
                                                     const float* __restrict__ x,
                                                     u16* __restrict__ xh,
                                                     int E, int NB, int total4, int nthreads) {
    __shared__ u32 h[256];
    int t = threadIdx.x;
    int b = blockIdx.x;
    h[t] = 0;
    __syncthreads();
    int base = b * 1024;
#pragma unroll
    for (int u = 0; u < 4; u++) {
        int e = base + u * 256 + t;
        if (e < E) {
            int r = row[e];
            atomicAdd(&h[r >> 8], 1u);
        }
    }
    __syncthreads();
    hoff[(size_t)b * 256 + t] = h[t];   // block-major, coalesced

    // fused x -> bf16 convert (grid-stride)
    int gtid = b * 256 + t;
    for (int i = gtid; i < total4; i += nthreads) {
        float4 v = *(const float4*)(x + (size_t)i * 4);
        ushort4 o;
        o.x = f2bf_rne(v.x); o.y = f2bf_rne(v.y);
        o.z = f2bf_rne(v.z); o.w = f2bf_rne(v.w);
        *(ushort4*)(xh + (size_t)i * 4) = o;
    }
}

// --- scanA: one block per digit d; exclusive scan of hoff[b][d] over blocks
// (in-place), digit total -> T[d]. ---
__global__ __launch_bounds__(256) void scanA_kernel(u32* __restrict__ hoff,
                                                    u32* __restrict__ T, int NB) {
    __shared__ u32 s[256];
    int t = threadIdx.x;
    int d = blockIdx.x;
    u32 carry = 0;
    int nchunk = (NB + 255) / 256;
    for (int ch = 0; ch < nchunk; ch++) {
        int idx = ch * 256 + t;
        u32 v = (idx < NB) ? hoff[(size_t)idx * 256 + d] : 0;
        s[t] = v;
        __syncthreads();
        for (int off = 1; off < 256; off <<= 1) {
            u32 u = (t >= off) ? s[t - off] : 0;
            __syncthreads();
            s[t] += u;
            __syncthreads();
        }
        if (idx < NB) hoff[(size_t)idx * 256 + d] = carry + s[t] - v;  // exclusive
        u32 tot = s[255];
        __syncthreads();
        carry += tot;
    }
    if (t == 0) T[d] = carry;
}

// --- scanB: exclusive scan of 256 digit totals -> Tpre[257]; rowptr[N]=E ---
__global__ __launch_bounds__(256) void scanB_kernel(const u32* __restrict__ T,
                                                    u32* __restrict__ Tpre,
                                                    int* __restrict__ rowptr, int N) {
    __shared__ u32 s[256];
    int t = threadIdx.x;
    u32 v = T[t];
    s[t] = v;
    __syncthreads();
    for (int off = 1; off < 256; off <<= 1) {
        u32 u = (t >= off) ? s[t - off] : 0;
        __syncthreads();
        s[t] += u;
        __syncthreads();
    }
    Tpre[t] = s[t] - v;
    if (t == 255) {
        Tpre[256] = s[255];
        rowptr[N] = (int)s[255];
    }
}

// --- P1 scatter: place edges into their row>>8 bucket. Within-bucket order
// arbitrary (LDS returning atomics) — legal for an MSD pass. Payload packs
// (row<<16)|col in high 32 bits, ew bits in low 32. ---
__global__ __launch_bounds__(256) void p1scatter_kernel(const int* __restrict__ row,
                                                        const int* __restrict__ col,
                                                        const float* __restrict__ ew,
                                                        const u32* __restrict__ hoff, // [NB][256] excl
                                                        const u32* __restrict__ Tpre,
                                                        u64* __restrict__ pay,
                                                        int E) {
    __shared__ u32 cur[256];
    int t = threadIdx.x;
    int b = blockIdx.x;
    cur[t] = Tpre[t] + hoff[(size_t)b * 256 + t];
    __syncthreads();
    int base = b * 1024;
#pragma unroll
    for (int u = 0; u < 4; u++) {
        int e = base + u * 256 + t;
        if (e < E) {
            u32 r = (u32)row[e];
            u32 c = (u32)col[e];
            u32 rc = (r << 16) | c;
            u32 pos = atomicAdd(&cur[r >> 8], 1u);
            pay[pos] = ((u64)rc << 32) | (u64)__float_as_uint(ew[e]);
        }
    }
}

// --- P2: per-bucket counting sort by row&255 into final CSR; writes rowptr
// for this bucket's 256 rows, deg sums (LDS f32 atomics) -> dis.
// ewc.y stores PURE col index (row stripped) for the SpMM passes. ---
__global__ __launch_bounds__(256) void p2_kernel(const u64* __restrict__ pay,
                                                 const u32* __restrict__ Tpre,
                                                 int* __restrict__ rowptr,
                                                 float* __restrict__ dis,
                                                 float2* __restrict__ ewc,
                                                 int N) {
    __shared__ u32 h[256];
    __shared__ u32 s[256];
    __shared__ u32 cur[256];
    __shared__ float dsum[256];
    int t = threadIdx.x;
    int bk = blockIdx.x;
    u32 base = Tpre[bk];
    u32 cnt = Tpre[bk + 1] - base;

    h[t] = 0;
    dsum[t] = 0.0f;
    __syncthreads();
    for (u32 j = t; j < cnt; j += 256) {
        u64 v = pay[base + j];
        u32 lr = (u32)(v >> 48) & 255u;   // row & 255 (row>>8 == bk here)
        atomicAdd(&h[lr], 1u);
    }
    __syncthreads();
    // exclusive scan of h
    u32 hv = h[t];
    s[t] = hv;
    __syncthreads();
    for (int off = 1; off < 256; off <<= 1) {
        u32 u = (t >= off) ? s[t - off] : 0;
        __syncthreads();
        s[t] += u;
        __syncthreads();
    }
    u32 p = s[t] - hv;   // exclusive
    int r = bk * 256 + t;
    if (r < N) rowptr[r] = (int)(base + p);
    cur[t] = base + p;
    __syncthreads();
    for (u32 j = t; j < cnt; j += 256) {
        u64 v = pay[base + j];
        u32 rc = (u32)(v >> 32);
        u32 lr = (rc >> 16) & 255u;
        float w = __uint_as_float((u32)v);
        u32 pos = atomicAdd(&cur[lr], 1u);
        ewc[pos] = make_float2(w, __uint_as_float(rc & 0xffffu));  // pure col
        atomicAdd(&dsum[lr], w);
    }
    __syncthreads();
    if (r < N) {
        float dv = dsum[t];
        dis[r] = (dv > 0.0f) ? rsqrtf(dv) : 0.0f;
    }
}

// ============================================================================
// CSR SpMM v2: half-wave per row (2 rows/wave), quarter-16 per edge,
// u64 (4-channel) gathers, LDS edge staging (no shuffle chains).
// NORM=1: pass 1 — applies w = -dis[r]*ew*dis[c] at stage time and writes
// the normalized edge back to ewc for pass 2. No __syncthreads (per-wave LDS).
// ============================================================================
template <int NORM>
__global__ __launch_bounds__(256) void spmm2_kernel(
        const int* __restrict__ rowptr,
        float2* __restrict__ ewc,
        const float* __restrict__ dis,
        const u64* __restrict__ h64,        // bf16 [N][64] viewed as [N][16] u64
        float* __restrict__ out32,          // fp32 [N][C]
        u64* __restrict__ outbf,            // bf16 [N][64] viewed as [N][16] u64... written as [N][32]u32 pairs
        int N) {
    __shared__ float2 eds[8][32];           // per half-wave staging (2 KB)

    int tid  = threadIdx.x;
    int hw   = tid >> 5;                    // half-wave slot in block 0..7
    int l32  = tid & 31;                    // lane within half
    int e2   = l32 >> 4;                    // edge selector within pair
    int cq   = l32 & 15;                    // channel quad (4 bf16 via u64)

    int row = blockIdx.x * 8 + hw;
    if (row >= N) return;

    int beg = rowptr[row];
    int end = rowptr[row + 1];
    float disr = NORM ? dis[row] : 0.0f;

    float a0 = 0.f, a1 = 0.f, a2 = 0.f, a3 = 0.f;

    for (int base = beg; base < end; base += 32) {
        int idx = base + l32;
        bool valid = idx < end;
        float2 ed = valid ? ewc[idx] : make_float2(0.0f, __uint_as_float(0));
        if (NORM) {
            u32 c = __float_as_uint(ed.y);
            float w = -disr * ed.x * dis[c];
            ed = make_float2(w, __uint_as_float(c));
            if (valid) ewc[idx] = ed;       // write back normalized for pass 2
        }
        eds[hw][l32] = ed;                  // same-wave: lgkmcnt ordering suffices
        int cnt = end - base; if (cnt > 32) cnt = 32;
        for (int j = 0; j < cnt; j += 4) {
            float2 f0 = eds[hw][j + e2];        // broadcast to 16 lanes
            float2 f1 = eds[hw][j + 2 + e2];
            u32 c0 = __float_as_uint(f0.y);
            u32 c1 = __float_as_uint(f1.y);
            u64 hv0 = h64[(size_t)c0 * 16 + cq];
            u64 hv1 = h64[(size_t)c1 * 16 + cq];
            float w0 = f0.x, w1 = f1.x;
            u32 lo0 = (u32)hv0, hi0 = (u32)(hv0 >> 32);
            u32 lo1 = (u32)hv1, hi1 = (u32)(hv1 >> 32);
            a0 = fmaf(w0, bf2f((u16)(lo0 & 0xffffu)), a0);
            a1 = fmaf(w0, bf2f((u16)(lo0 >> 16)),     a1);
            a2 = fmaf(w0, bf2f((u16)(hi0 & 0xffffu)), a2);
            a3 = fmaf(w0, bf2f((u16)(hi0 >> 16)),     a3);
            a0 = fmaf(w1, bf2f((u16)(lo1 & 0xffffu)), a0);
            a1 = fmaf(w1, bf2f((u16)(lo1 >> 16)),     a1);
            a2 = fmaf(w1, bf2f((u16)(hi1 & 0xffffu)), a2);
            a3 = fmaf(w1, bf2f((u16)(hi1 >> 16)),     a3);
        }
    }

    // combine the two edge-quarters (partner lane = l32 ^ 16, same half)
    a0 += __shfl_xor(a0, 16);
    a1 += __shfl_xor(a1, 16);
    a2 += __shfl_xor(a2, 16);
    a3 += __shfl_xor(a3, 16);

    if (e2 == 0) {
        float4 o = make_float4(a0, a1, a2, a3);
        *(float4*)(out32 + (size_t)row * C + 4 * cq) = o;
        u32 p0 = (u32)f2bf_rne(a0) | ((u32)f2bf_rne(a1) << 16);
        u32 p1 = (u32)f2bf_rne(a2) | ((u32)f2bf_rne(a3) << 16);
        outbf[(size_t)row * 16 + cq] = (u64)p0 | ((u64)p1 << 32);
    }
}

// --- fused dense epilogue as register-tiled GEMM ---
// out = relu([x | T1 | 2P-x] @ Wcat + b), Wcat = [192][64] (W row-major)
__global__ __launch_bounds__(256) void final_gemm_kernel(
        const float* __restrict__ x,
        const float* __restrict__ T1,
        const float* __restrict__ P,
        const float* __restrict__ W,   // [192][64] row-major
        const float* __restrict__ b,
        float* __restrict__ out, int N) {
    __shared__ float As[16][64];  // [k][node]
    __shared__ float Ws[16][64];  // [k][col]

    int t  = threadIdx.x;
    int tx = t & 15;
    int ty = t >> 4;
    int n0 = blockIdx.x * 64;

    int sn = t >> 2;
    int skb = (t & 3) * 4;

    float acc[4][4];
#pragma unroll
    for (int i = 0; i < 4; i++)
#pragma unroll
        for (int j = 0; j < 4; j++) acc[i][j] = 0.0f;

#pragma unroll 1
    for (int s = 0; s < 12; s++) {
        float4 wv = *(const float4*)(W + s * 1024 + t * 4);
        int nn = n0 + sn;
        float4 av = make_float4(0.f, 0.f, 0.f, 0.f);
        if (nn < N) {
            if (s < 4) {
                av = *(const float4*)(x + (size_t)nn * C + s * 16 + skb);
            } else if (s < 8) {
                av = *(const float4*)(T1 + (size_t)nn * C + (s - 4) * 16 + skb);
            } else {
                float4 pv = *(const float4*)(P + (size_t)nn * C + (s - 8) * 16 + skb);
                float4 xv = *(const float4*)(x + (size_t)nn * C + (s - 8) * 16 + skb);
                av = make_float4(2.0f * pv.x - xv.x, 2.0f * pv.y - xv.y,
                                 2.0f * pv.z - xv.z, 2.0f * pv.w - xv.w);
            }
        }
        __syncthreads();
        {
            int wk = (t * 4) >> 6;
            int wc = (t * 4) & 63;
            *(float4*)&Ws[wk][wc] = wv;
        }
        As[skb + 0][sn] = av.x;
        As[skb + 1][sn] = av.y;
        As[skb + 2][sn] = av.z;
        As[skb + 3][sn] = av.w;
        __syncthreads();

#pragma unroll
        for (int kk = 0; kk < 16; kk++) {
            float4 a4 = *(const float4*)&As[kk][ty * 4];
            float4 w4 = *(const float4*)&Ws[kk][tx * 4];
            float ar[4] = {a4.x, a4.y, a4.z, a4.w};
            float wr[4] = {w4.x, w4.y, w4.z, w4.w};
#pragma unroll
            for (int i = 0; i < 4; i++)
#pragma unroll
                for (int j = 0; j < 4; j++)
                    acc[i][j] = fmaf(ar[i], wr[j], acc[i][j]);
        }
    }

    float4 bv = *(const float4*)(b + tx * 4);
    float br[4] = {bv.x, bv.y, bv.z, bv.w};
#pragma unroll
    for (int i = 0; i < 4; i++) {
        int node = n0 + ty * 4 + i;
        if (node < N) {
            float4 o;
            o.x = fmaxf(acc[i][0] + br[0], 0.0f);
            o.y = fmaxf(acc[i][1] + br[1], 0.0f);
            o.z = fmaxf(acc[i][2] + br[2], 0.0f);
            o.w = fmaxf(acc[i][3] + br[3], 0.0f);
            *(float4*)(out + (size_t)node * C + tx * 4) = o;
        }
    }
}

extern "C" void kernel_launch(void* const* d_in, const int* in_sizes, int n_in,
                              void* d_out, int out_size, void* d_ws, size_t ws_size,
                              hipStream_t stream) {
    const float* x  = (const float*)d_in[0];
    const int*   ei = (const int*)d_in[1];
    const float* ew = (const float*)d_in[2];
    const float* W  = (const float*)d_in[3];
    const float* b  = (const float*)d_in[4];
    float* out = (float*)d_out;

    const int N = in_sizes[0] / C;
    const int E = in_sizes[2];
    const int* row = ei;        // edge_index[0]
    const int* col = ei + E;    // edge_index[1]

    char* ws = (char*)d_ws;
    size_t off = 0;
    auto alloc = [&](size_t bytes) {
        void* p = ws + off;
        off = (off + bytes + 255) & ~(size_t)255;
        return p;
    };
    const int NB = (E + 1023) / 1024;        // histogram/partition blocks
    const int NBUCK = (N + 255) / 256;       // row buckets (196)

    float*  dis    = (float*)alloc((size_t)N * 4);
    int*    rowptr = (int*)alloc((size_t)(N + 1) * 4);
    float2* ewc    = (float2*)alloc((size_t)E * 8);
    u64*    pay    = (u64*)alloc((size_t)E * 8);
    float*  T1     = (float*)alloc((size_t)N * C * 4);
    float*  P      = (float*)alloc((size_t)N * C * 4);
    u32*    hoff   = (u32*)alloc((size_t)NB * 256 * 4);
    u32*    T      = (u32*)alloc((size_t)256 * 4);
    u32*    Tpre   = (u32*)alloc((size_t)257 * 4);
    u16*    xh     = (u16*)alloc((size_t)N * C * 2);
    u16*    T1h    = (u16*)alloc((size_t)N * C * 2);
    u16*    Ph     = (u16*)alloc((size_t)N * C * 2);  // bf16 sink for spmm2

    const int B = 256;
    int total4 = N * C / 4;

    p1hist_kernel<<<NB, B, 0, stream>>>(row, hoff, x, xh, E, NB, total4, NB * B);
    scanA_kernel<<<256, B, 0, stream>>>(hoff, T, NB);
    scanB_kernel<<<1, B, 0, stream>>>(T, Tpre, rowptr, N);
    p1scatter_kernel<<<NB, B, 0, stream>>>(row, col, ew, hoff, Tpre, pay, E);
    p2_kernel<<<NBUCK, B, 0, stream>>>(pay, Tpre, rowptr, dis, ewc, N);

    int spmm_blocks = (N + 7) / 8;           // 8 rows per block (half-wave per row)
    spmm2_kernel<1><<<spmm_blocks, B, 0, stream>>>(rowptr, ewc, dis, (const u64*)xh,
                                                   T1, (u64*)T1h, N);
    spmm2_kernel<0><<<spmm_blocks, B, 0, stream>>>(rowptr, ewc, dis, (const u64*)T1h,
                                                   P, (u64*)Ph, N);

    final_gemm_kernel<<<(N + 63) / 64, B, 0, stream>>>(x, T1, P, W, b, out, N);
}